// Round 13
// baseline (87.844 us; speedup 1.0000x reference)
//
#include <hip/hip_runtime.h>

// FBPinn 1D, NW=16 windows, MLP 1->64->64->64->1 (tanh), sigmoid windows.
// R13: ONE normal kernel, block-LOCAL bucketing (no grid sync, no coop
//      launch, no d_ws). Block (seg,w) scans slice x[seg*chunk..) (6KB),
//      compacts points strictly inside window w into LDS, then runs the
//      R11-verified MFMA pipeline on them (usually one 128-pt round).
//      16x scan redundancy = 6.4MB L2 reads ~ 1us. Nodes: memset(out)+kernel.
// [R12: hipLaunchCooperativeKernel silently failed (out never written) —
//  unverifiable launch mode, abandoned.]
// [R11 verified math: v_mfma_f32_16x16x32_f16; C/D col=lane&15,
//  row=(lane>>4)*4+reg; A/B m|n=lane&15, k=(lane>>4)*8+j. Cross-lane LDS
//  (Hp) handoff needs compiler fences at DS phase transitions (R9 lesson).]

#define NW    16
#define NEUR  64
#define BLK   256
#define NSEG  64                 // slices; chunk = ceil(100000/64) = 1563
#define LCAP  1600               // >= chunk: LDS idx buffer can't overflow
#define DSFENCE() asm volatile("" ::: "memory")

typedef _Float16 v8h __attribute__((ext_vector_type(8)));
typedef float    v4f __attribute__((ext_vector_type(4)));
typedef _Float16 h2  __attribute__((ext_vector_type(2)));
typedef unsigned v4u __attribute__((ext_vector_type(4)));

__device__ __forceinline__ float fast_tanh(float x) {
    float e = __expf(x + x);
    return 1.0f - 2.0f * __builtin_amdgcn_rcpf(e + 1.0f);
}
__device__ __forceinline__ float fast_sigmoid(float z) {
    return __builtin_amdgcn_rcpf(1.0f + __expf(-z));
}
__device__ __forceinline__ v8h zero8() {
    v8h z;
    #pragma unroll
    for (int j = 0; j < 8; ++j) z[j] = (_Float16)0.0f;
    return z;
}

__global__ __launch_bounds__(256, 3) void fused_fbpinn(
    const float* __restrict__ x,
    const float* __restrict__ W_in, const float* __restrict__ b_in,
    const float* __restrict__ W_h,  const float* __restrict__ b_h,
    const float* __restrict__ W_out, const float* __restrict__ b_out,
    float* __restrict__ out, int n) {
    __shared__ _Float16 aH[16 * 512];     // hidden A-frags, 16 KB
    __shared__ _Float16 aIn[4 * 512];     //                  4 KB
    __shared__ _Float16 aOut[2 * 512];    //                  2 KB
    __shared__ float    biasH[128];
    __shared__ unsigned Hp[4 * 1024];     // [wid][t][k2][n16], 16 KB
    __shared__ int      lidx[LCAP];       // slice points in this window
    __shared__ int      scnt;

    const int tid  = threadIdx.x;
    const int seg  = blockIdx.x;
    const int w    = blockIdx.y;
    const int lane = tid & 63;
    const int wid  = tid >> 6;
    const int n16  = lane & 15;
    const int quad = lane >> 4;

    float lo = (w == 0)      ? 0.0f   : ((float)w - 0.125f) * 6.25f;
    float hi = (w == NW - 1) ? 100.0f : ((float)w + 1.125f) * 6.25f;

    // ---- block-local bucketing: scan own slice for own window ----
    if (tid == 0) scnt = 0;
    __syncthreads();
    {
        const int chunk = (n + NSEG - 1) / NSEG;
        const int i0 = seg * chunk;
        const int i1 = min(n, i0 + chunk);
        for (int i = i0 + tid; i < i1; i += BLK) {
            float xv = x[i];
            if (lo < xv && xv < hi) {              // exact strict compares
                int p = atomicAdd(&scnt, 1);       // LDS atomic: cheap
                lidx[p] = i;
            }
        }
    }

    // ---- prepack A-fragments (overlaps the scan; synced below) ----
    #pragma unroll
    for (int p = 0; p < 4; ++p) {                  // hidden: 16 frags
        int f  = wid * 4 + p;                      // f = l*8 + mt*2 + ks
        int l  = f >> 3, mt = (f >> 1) & 3, ks = f & 1;
        const float* Ws = W_h + (l * NW + w) * 4096;
        int m  = mt * 16 + n16;
        int k0 = ks * 32 + quad * 8;
        v8h a;
        #pragma unroll
        for (int j = 0; j < 8; ++j)
            a[j] = (_Float16)Ws[(k0 + j) * 64 + m];   // A[m][k]=W[k][m]
        *(v8h*)(&aH[f * 512 + lane * 8]) = a;
    }
    {   // input frags: A[m][0]=Wi[m], A[m][1]=bi[m]
        int mt = wid, m = mt * 16 + n16;
        v8h a = zero8();
        if (quad == 0) {
            a[0] = (_Float16)W_in[w * 64 + m];
            a[1] = (_Float16)b_in[w * 64 + m];
        }
        *(v8h*)(&aIn[mt * 512 + lane * 8]) = a;
    }
    if (wid < 2) {  // output frags: A[0][k]=Wo[k]
        int ks = wid;
        v8h a = zero8();
        if (n16 == 0) {
            int k0 = ks * 32 + quad * 8;
            #pragma unroll
            for (int j = 0; j < 8; ++j)
                a[j] = (_Float16)W_out[w * 64 + k0 + j];
        }
        *(v8h*)(&aOut[ks * 512 + lane * 8]) = a;
    }
    if (tid < 128)
        biasH[tid] = b_h[((tid >> 6) * NW + w) * 64 + (tid & 63)];
    __syncthreads();

    const int m_cnt = scnt;
    if (m_cnt == 0) return;

    float mean    = 0.5f * (lo + hi);
    float inv_std = 1.0f / (0.5f * (hi - lo));
    float ow0 = (float)w * 6.25f;                  // ovm[w] exactly
    float ow1 = (float)(w + 1) * 6.25f;
    float bo  = b_out[w];

    unsigned* HpW = Hp + wid * 1024;               // tile t at offset t*512

    for (int base = 0; base < m_cnt; base += 128) {
        float xv[2], xn[2];
        bool  act[2];
        int   idx[2];
        #pragma unroll
        for (int t = 0; t < 2; ++t) {
            int kpt = base + wid * 32 + t * 16 + n16;
            act[t]  = (kpt < m_cnt) && (lane < 16);
            int kk  = (kpt < m_cnt) ? kpt : 0;
            int id  = lidx[kk];
            idx[t] = id;
            xv[t]  = x[id];
            xn[t]  = (xv[t] - mean) * inv_std;
        }

        // input layer: pre = Wi*xn + bi, tanh -> Hp
        {
            v8h b[2];
            #pragma unroll
            for (int t = 0; t < 2; ++t) {
                b[t] = zero8();
                if (quad == 0) { b[t][0] = (_Float16)xn[t]; b[t][1] = (_Float16)1.0f; }
            }
            #pragma unroll
            for (int mt = 0; mt < 4; ++mt) {
                v8h a = *(const v8h*)(&aIn[mt * 512 + lane * 8]);
                #pragma unroll
                for (int t = 0; t < 2; ++t) {
                    v4f c = {0.0f, 0.0f, 0.0f, 0.0f};
                    c = __builtin_amdgcn_mfma_f32_16x16x32_f16(a, b[t], c, 0, 0, 0);
                    int k2 = mt * 8 + quad * 2;    // pair rows, m0 even
                    h2 q0, q1;
                    q0[0] = (_Float16)fast_tanh(c[0]);
                    q0[1] = (_Float16)fast_tanh(c[1]);
                    q1[0] = (_Float16)fast_tanh(c[2]);
                    q1[1] = (_Float16)fast_tanh(c[3]);
                    HpW[t * 512 + k2 * 16 + n16]       = __builtin_bit_cast(unsigned, q0);
                    HpW[t * 512 + (k2 + 1) * 16 + n16] = __builtin_bit_cast(unsigned, q1);
                }
            }
        }
        DSFENCE();   // writes(input) -> reads(hidden0)

        #pragma unroll
        for (int l = 0; l < 2; ++l) {
            v4f d[2][4];
            #pragma unroll
            for (int t = 0; t < 2; ++t)
                #pragma unroll
                for (int mt = 0; mt < 4; ++mt)
                    d[t][mt] = (v4f){0.0f, 0.0f, 0.0f, 0.0f};
            #pragma unroll
            for (int ks = 0; ks < 2; ++ks) {
                v8h b[2];
                #pragma unroll
                for (int t = 0; t < 2; ++t) {
                    v4u bw;
                    #pragma unroll
                    for (int j2 = 0; j2 < 4; ++j2)
                        bw[j2] = HpW[t * 512 + (ks * 16 + quad * 4 + j2) * 16 + n16];
                    b[t] = __builtin_bit_cast(v8h, bw);
                }
                #pragma unroll
                for (int mt = 0; mt < 4; ++mt) {
                    v8h a = *(const v8h*)(&aH[(l * 8 + mt * 2 + ks) * 512 + lane * 8]);
                    #pragma unroll
                    for (int t = 0; t < 2; ++t)
                        d[t][mt] = __builtin_amdgcn_mfma_f32_16x16x32_f16(
                                       a, b[t], d[t][mt], 0, 0, 0);
                }
            }
            DSFENCE();   // reads(layer l) -> writes(layer l)
            const float* bl = biasH + l * 64;
            #pragma unroll
            for (int t = 0; t < 2; ++t) {
                #pragma unroll
                for (int mt = 0; mt < 4; ++mt) {
                    int m0 = mt * 16 + quad * 4;   // even
                    int k2 = m0 >> 1;
                    h2 q0, q1;
                    q0[0] = (_Float16)fast_tanh(d[t][mt][0] + bl[m0]);
                    q0[1] = (_Float16)fast_tanh(d[t][mt][1] + bl[m0 + 1]);
                    q1[0] = (_Float16)fast_tanh(d[t][mt][2] + bl[m0 + 2]);
                    q1[1] = (_Float16)fast_tanh(d[t][mt][3] + bl[m0 + 3]);
                    HpW[t * 512 + k2 * 16 + n16]       = __builtin_bit_cast(unsigned, q0);
                    HpW[t * 512 + (k2 + 1) * 16 + n16] = __builtin_bit_cast(unsigned, q1);
                }
            }
            DSFENCE();   // writes(layer l) -> reads(next phase)
        }

        // output layer: A row0 = Wo -> e[0] on lanes 0..15
        {
            v4f e[2] = {{0.0f,0.0f,0.0f,0.0f}, {0.0f,0.0f,0.0f,0.0f}};
            #pragma unroll
            for (int ks = 0; ks < 2; ++ks) {
                v8h a = *(const v8h*)(&aOut[ks * 512 + lane * 8]);
                #pragma unroll
                for (int t = 0; t < 2; ++t) {
                    v4u bw;
                    #pragma unroll
                    for (int j2 = 0; j2 < 4; ++j2)
                        bw[j2] = HpW[t * 512 + (ks * 16 + quad * 4 + j2) * 16 + n16];
                    v8h b = __builtin_bit_cast(v8h, bw);
                    e[t] = __builtin_amdgcn_mfma_f32_16x16x32_f16(a, b, e[t], 0, 0, 0);
                }
            }
            #pragma unroll
            for (int t = 0; t < 2; ++t) {
                float outv = e[t][0] + bo;
                float win = fast_sigmoid((xv[t] - ow0) * 2.0f) *
                            fast_sigmoid((ow1 - xv[t]) * 2.0f);
                if (act[t]) atomicAdd(&out[idx[t]], win * outv);
            }
        }
        DSFENCE();   // Hp reuse across rounds
    }
}

extern "C" void kernel_launch(void* const* d_in, const int* in_sizes, int n_in,
                              void* d_out, int out_size, void* d_ws, size_t ws_size,
                              hipStream_t stream) {
    const float* x     = (const float*)d_in[0];
    const float* W_in  = (const float*)d_in[1];
    const float* b_in  = (const float*)d_in[2];
    const float* W_h   = (const float*)d_in[3];
    const float* b_h   = (const float*)d_in[4];
    const float* W_out = (const float*)d_in[5];
    const float* b_out = (const float*)d_in[6];
    float* out = (float*)d_out;
    const int n = in_sizes[0];

    hipMemsetAsync(out, 0, (size_t)n * sizeof(float), stream);

    dim3 grid(NSEG, NW);   // 1024 blocks
    fused_fbpinn<<<grid, BLK, 0, stream>>>(x, W_in, b_in, W_h, b_h,
                                           W_out, b_out, out, n);
}